// Round 4
// baseline (79.146 us; speedup 1.0000x reference)
//
#include <hip/hip_runtime.h>
#include <math.h>

#define KSZ   17
#define PADR  8
#define FDIM  100
#define ODIM  180
#define HTOT  512
#define WTOT  512
#define TILE  16
#define LDSW  48
#define RPB   8            // pixel rows per block (z-split: 2 blocks cover a 16x16 tile)
#define TEMPERATURE 20.0f
#define THRESHOLD   55.0f

// ---- order-preserving float<->uint encoding for atomic min/max ----
__device__ __forceinline__ unsigned int fenc(float f) {
    unsigned int u = __float_as_uint(f);
    return (u & 0x80000000u) ? ~u : (u | 0x80000000u);
}
__device__ __forceinline__ float fdec(unsigned int k) {
    unsigned int u = (k & 0x80000000u) ? (k ^ 0x80000000u) : ~k;
    return __uint_as_float(u);
}

__global__ __launch_bounds__(256) void filter_main(
    const float* __restrict__ x,
    const int*   __restrict__ freq,
    const int*   __restrict__ orient,
    const float* __restrict__ fb,
    float*       __restrict__ y,
    unsigned int* __restrict__ mm)
{
    __shared__ float tile[RPB + 16][LDSW];   // 24 x 48 floats
    __shared__ int   sidx[RPB * 16];         // per-pixel filter index (128)
    __shared__ float sacc[RPB * 16];         // per-pixel correlation result

    const int bx = blockIdx.x, by = blockIdx.y, bz = blockIdx.z;
    const int tid = threadIdx.x;

    // per-pixel clamped filter index -> LDS (128 pixels: rows bz*8 .. +7)
    if (tid < RPB * 16) {
        const int pr = tid >> 4, pc = tid & 15;
        const int gp = (by * TILE + bz * RPB + pr) * WTOT + bx * TILE + pc;
        int f0 = freq[gp] - 1;
        int o0 = orient[gp] - 1;
        f0 = f0 < 0 ? 0 : (f0 > FDIM - 1 ? FDIM - 1 : f0);
        o0 = o0 < 0 ? 0 : (o0 > ODIM - 1 ? ODIM - 1 : o0);
        sidx[tid] = f0 * ODIM + o0;
    }

    // stage 24x32 input region (zero-padded at image borders)
    const int h0 = by * TILE + bz * RPB - PADR;
    const int w0 = bx * TILE - PADR;
    for (int i = tid; i < (RPB + 16) * 32; i += 256) {
        const int r = i >> 5, c = i & 31;
        const int gh = h0 + r, gw = w0 + c;
        float v = 0.f;
        if (gh >= 0 && gh < HTOT && gw >= 0 && gw < WTOT)
            v = x[gh * WTOT + gw];
        tile[r][c] = v;
    }
    __syncthreads();

    // ---- cooperative correlation: 16 lanes per pixel, prefetched filters ----
    const int l  = tid & 15;                 // lane within quarter-wave
    const int qw = tid >> 4;                 // quarter-wave id = pixel column

    int offs[18];
    #pragma unroll
    for (int j = 0; j < 18; ++j) {
        const int e = j * 16 + l;
        offs[j] = (e / 17) * LDSW + (e % 17);
    }

    float mn =  3.4e38f, mx = -3.4e38f;

    // prefetch filter values for it = 0
    float ka[19];
    {
        const float* __restrict__ kf = fb + (size_t)sidx[qw] * 289;
        #pragma unroll
        for (int j = 0; j < 18; ++j) ka[j] = kf[j * 16 + l];
        ka[18] = kf[288];
    }

    #pragma unroll
    for (int it = 0; it < RPB; ++it) {
        // issue next pixel's filter loads (hide latency under this pixel's math)
        float kb[19];
        if (it < RPB - 1) {
            const float* __restrict__ kf = fb + (size_t)sidx[(it + 1) * 16 + qw] * 289;
            #pragma unroll
            for (int j = 0; j < 18; ++j) kb[j] = kf[j * 16 + l];
            kb[18] = kf[288];
        }

        const float* __restrict__ base = &tile[it][qw];
        float a0 = 0.f, a1 = 0.f, a2 = 0.f, a3 = 0.f;
        #pragma unroll
        for (int j = 0; j < 16; j += 4) {
            a0 = fmaf(ka[j    ], base[offs[j    ]], a0);
            a1 = fmaf(ka[j + 1], base[offs[j + 1]], a1);
            a2 = fmaf(ka[j + 2], base[offs[j + 2]], a2);
            a3 = fmaf(ka[j + 3], base[offs[j + 3]], a3);
        }
        a0 = fmaf(ka[16], base[offs[16]], a0);
        a1 = fmaf(ka[17], base[offs[17]], a1);
        float acc = (a0 + a1) + (a2 + a3);
        if (l == 0) acc = fmaf(ka[18], base[16 * LDSW + 16], acc);  // e = 288 tail

        // butterfly sum over the 16-lane group
        #pragma unroll
        for (int off = 8; off; off >>= 1)
            acc += __shfl_xor(acc, off, 64);

        if (l == 0) sacc[it * 16 + qw] = acc;
        mn = fminf(mn, acc);
        mx = fmaxf(mx, acc);

        if (it < RPB - 1) {
            #pragma unroll
            for (int j = 0; j < 19; ++j) ka[j] = kb[j];
        }
    }
    __syncthreads();

    // coalesced y store (128 consecutive addresses)
    if (tid < RPB * 16) {
        const int pr = tid >> 4, pc = tid & 15;
        y[(by * TILE + bz * RPB + pr) * WTOT + bx * TILE + pc] = sacc[tid];
    }

    // ---- block min/max reduce, one atomic pair per block ----
    #pragma unroll
    for (int off = 32; off > 0; off >>= 1) {
        mn = fminf(mn, __shfl_down(mn, off, 64));
        mx = fmaxf(mx, __shfl_down(mx, off, 64));
    }
    __shared__ float smn[4], smx[4];
    const int wid = tid >> 6, lane = tid & 63;
    if (lane == 0) { smn[wid] = mn; smx[wid] = mx; }
    __syncthreads();
    if (tid == 0) {
        float bmn = smn[0], bmx = smx[0];
        #pragma unroll
        for (int i = 1; i < 4; ++i) {
            bmn = fminf(bmn, smn[i]);
            bmx = fmaxf(bmx, smx[i]);
        }
        atomicMin(&mm[0], fenc(bmn));
        atomicMax(&mm[1], fenc(bmx));
    }
}

__global__ __launch_bounds__(256) void filter_final(
    float* __restrict__ y,
    const unsigned int* __restrict__ mm)
{
    const int i = blockIdx.x * 256 + threadIdx.x;
    const float ymin = fdec(mm[0]);
    const float ymax = fdec(mm[1]);
    const float rng  = fmaxf(ymax - ymin, 1e-8f);

    const float v  = y[i];
    const float o1 = 100.f * (v - ymin) / rng;                     // in [0,100]
    const float s  = 100.f / (1.f + expf(-(TEMPERATURE * (o1 * 0.01f - THRESHOLD * 0.01f))));

    // analytic post-sigmoid extrema: o1 hits exactly 0 and 100 at argmin/argmax
    const float smin = 100.f / (1.f + expf( 11.f));   // 100*sigmoid(-11)
    const float smax = 100.f / (1.f + expf(-9.f));    // 100*sigmoid(+9)
    const float srng = fmaxf(smax - smin, 1e-8f);

    y[i] = 100.f * (s - smin) / srng;
}

extern "C" void kernel_launch(void* const* d_in, const int* in_sizes, int n_in,
                              void* d_out, int out_size, void* d_ws, size_t ws_size,
                              hipStream_t stream) {
    const float* x      = (const float*)d_in[0];
    const int*   freq   = (const int*)d_in[1];
    const int*   orient = (const int*)d_in[2];
    const float* fb     = (const float*)d_in[3];
    float*       out    = (float*)d_out;           // doubles as y scratch
    unsigned int* mm    = (unsigned int*)d_ws;     // [0]=enc(min), [1]=enc(max)

    hipMemsetAsync(mm, 0xFF, 4, stream);
    hipMemsetAsync((char*)d_ws + 4, 0x00, 4, stream);

    dim3 grid(WTOT / TILE, HTOT / TILE, TILE / RPB);   // 32 x 32 x 2 blocks
    filter_main<<<grid, 256, 0, stream>>>(x, freq, orient, fb, out, mm);

    filter_final<<<(HTOT * WTOT) / 256, 256, 0, stream>>>(out, mm);
}